// Round 1
// baseline (46.852 us; speedup 1.0000x reference)
//
#include <hip/hip_runtime.h>
#include <hip/hip_bf16.h>
#include <stdint.h>

#define TSTEPS 4096
#define C_CHUNKS 64
#define L_STEPS 64   // TSTEPS / C_CHUNKS

__device__ __forceinline__ float fast_exp2(float x){ return __builtin_amdgcn_exp2f(x); }
__device__ __forceinline__ float fast_rcp(float x){ return __builtin_amdgcn_rcpf(x); }
__device__ __forceinline__ float sigmoid_f(float x){
  return fast_rcp(1.0f + fast_exp2(-1.4426950408889634f * x));
}
__device__ __forceinline__ float lane_bcast(float v, int l){
  return __builtin_bit_cast(float, __builtin_amdgcn_readlane(__builtin_bit_cast(int, v), l));
}

// K1: per (point, chunk) affine composition over L_STEPS steps.
// s_end = A * s_start + B
__global__ __launch_bounds__(256) void k1_affine(
    const float* __restrict__ h, const float* __restrict__ mesh,
    int N, int Np, float* __restrict__ Aw, float* __restrict__ Bw)
{
  const int tid  = threadIdx.x;
  const int i    = blockIdx.x * 256 + tid;
  const int c    = blockIdx.y;
  const int lane = tid & 63;
  const int t0   = c * L_STEPS;

  float beta = 0.f, alpha = 0.f;
  if (i < N) { beta = mesh[2*i]; alpha = mesh[2*i+1]; }
  const float K  = 144.26950408889634f;   // (1/temp) * log2(e)
  const float aK = alpha * K;
  const float bK = beta  * K;

  // per-lane h for this chunk; branch-direction mask (wave-uniform)
  const float hl = h[t0 + lane];
  const float hp = (t0 + lane > 0) ? h[t0 + lane - 1] : 0.0f;
  const uint64_t mask = __ballot(hl > hp);

  float A = 1.0f, B = 0.0f;
  #pragma unroll
  for (int tl = 0; tl < L_STEPS; ++tl) {
    const bool  up = (mask >> tl) & 1;
    const float ht = lane_bcast(hl, tl);
    const float kk = up ? -K : K;
    const float cc = up ? aK : -bK;
    const float e  = fast_exp2(fmaf(ht, kk, cc));
    const float g  = fast_rcp(1.0f + e);
    const float a  = 1.0f - g;
    const float b  = up ? g : -g;
    A = A * a;
    B = fmaf(a, B, b);
  }
  Aw[(size_t)c * Np + i] = A;
  Bw[(size_t)c * Np + i] = B;
}

// K2: sequential scan over chunks per point (writes chunk-start states),
// block 0 additionally reduces D = sum(sigmoid(raw_density)).
__global__ __launch_bounds__(256) void k2_scan(
    const float* __restrict__ Aw, const float* __restrict__ Bw,
    float* __restrict__ Sw, const float* __restrict__ raw_density,
    int N, int Np, float* __restrict__ Dws)
{
  const int tid = threadIdx.x;
  const int i   = blockIdx.x * 256 + tid;
  float s = -1.0f;
  #pragma unroll 8
  for (int c = 0; c < C_CHUNKS; ++c) {
    const size_t off = (size_t)c * Np + i;
    Sw[off] = s;
    s = fmaf(Aw[off], s, Bw[off]);
  }
  if (blockIdx.x == 0) {
    __shared__ float red[256];
    float loc = 0.f;
    for (int j = tid; j < N; j += 256) loc += sigmoid_f(raw_density[j]);
    red[tid] = loc;
    __syncthreads();
    for (int st = 128; st > 0; st >>= 1) {
      if (tid < st) red[tid] += red[tid + st];
      __syncthreads();
    }
    if (tid == 0) Dws[0] = red[0];
  }
}

// K3: recompute states per chunk with known start state, accumulate
// density-weighted contributions; butterfly transpose-reduce so lane l
// ends holding the wave's partial sum for t = t0 + l.
__global__ __launch_bounds__(256) void k3_states(
    const float* __restrict__ h, const float* __restrict__ mesh,
    const float* __restrict__ raw_density, const float* __restrict__ Sw,
    int N, int Np, float* __restrict__ Mpart)
{
  const int tid   = threadIdx.x;
  const int i     = blockIdx.x * 256 + tid;
  const int c     = blockIdx.y;
  const int lane  = tid & 63;
  const int wglob = blockIdx.x * 4 + (tid >> 6);
  const int t0    = c * L_STEPS;

  float beta = 0.f, alpha = 0.f, d = 0.f;
  if (i < N) { beta = mesh[2*i]; alpha = mesh[2*i+1]; d = sigmoid_f(raw_density[i]); }
  const float K  = 144.26950408889634f;
  const float aK = alpha * K;
  const float bK = beta  * K;

  const float hl = h[t0 + lane];
  const float hp = (t0 + lane > 0) ? h[t0 + lane - 1] : 0.0f;
  const uint64_t mask = __ballot(hl > hp);

  float s = Sw[(size_t)c * Np + i];
  float cur[L_STEPS];
  #pragma unroll
  for (int tl = 0; tl < L_STEPS; ++tl) {
    const bool  up = (mask >> tl) & 1;
    const float ht = lane_bcast(hl, tl);
    const float kk = up ? -K : K;
    const float cc = up ? aK : -bK;
    const float e  = fast_exp2(fmaf(ht, kk, cc));
    const float g  = fast_rcp(1.0f + e);
    const float a  = 1.0f - g;
    const float b  = up ? g : -g;
    s = fmaf(a, s, b);
    cur[tl] = d * s;
  }

  // butterfly transpose-reduce: after 6 stages lane l holds sum over the
  // wave's 64 points of cur[l] (static register indices only).
  #pragma unroll
  for (int k = 0; k < 6; ++k) {
    const int  m  = 1 << k;
    const bool bb = (lane >> k) & 1;
    #pragma unroll
    for (int j = 0; j < (L_STEPS >> (k + 1)); ++j) {
      const float x = bb ? cur[2*j + 1] : cur[2*j];
      const float y = bb ? cur[2*j]     : cur[2*j + 1];
      cur[j] = x + __shfl_xor(y, m, 64);
    }
  }
  Mpart[(size_t)wglob * TSTEPS + t0 + lane] = cur[0];
}

// K4: reduce wave-partials per t and apply the affine output map.
__global__ __launch_bounds__(256) void k4_final(
    const float* __restrict__ Mpart, const float* __restrict__ h,
    const float* __restrict__ Dws,
    const float* __restrict__ raw_offset, const float* __restrict__ raw_scale,
    const float* __restrict__ raw_slope,
    int W, float* __restrict__ out)
{
  const int t = blockIdx.x * 256 + threadIdx.x;
  if (t >= TSTEPS) return;
  float sum = 0.f;
  #pragma unroll 8
  for (int w = 0; w < W; ++w) sum += Mpart[(size_t)w * TSTEPS + t];
  const float D      = Dws[0];
  const float offset = -10.0f + 20.0f * sigmoid_f(raw_offset[0]);
  const float scale  = 20.0f * sigmoid_f(raw_scale[0]);
  const float slope  = -20.0f + 40.0f * sigmoid_f(raw_slope[0]);
  out[t] = scale * (sum / D) + fmaf(h[t], slope, offset);
}

extern "C" void kernel_launch(void* const* d_in, const int* in_sizes, int n_in,
                              void* d_out, int out_size, void* d_ws, size_t ws_size,
                              hipStream_t stream)
{
  const float* h           = (const float*)d_in[0];
  const float* mesh        = (const float*)d_in[1];
  const float* raw_density = (const float*)d_in[2];
  const float* raw_offset  = (const float*)d_in[3];
  const float* raw_scale   = (const float*)d_in[4];
  const float* raw_slope   = (const float*)d_in[5];
  float* out = (float*)d_out;

  const int N  = in_sizes[2];          // 5151 mesh points
  const int P  = (N + 255) / 256;      // point-blocks (21)
  const int Np = P * 256;              // padded points (5376)
  const int W  = Np / 64;              // waves over points (84)
  const int T  = TSTEPS;               // 4096

  float* ws    = (float*)d_ws;
  float* Aw    = ws;                                  // C*Np
  float* Bw    = Aw + (size_t)C_CHUNKS * Np;          // C*Np
  float* Sw    = Bw + (size_t)C_CHUNKS * Np;          // C*Np
  float* Mpart = Sw + (size_t)C_CHUNKS * Np;          // W*T
  float* Dws   = Mpart + (size_t)W * T;               // 1

  dim3 gridPC(P, C_CHUNKS);
  k1_affine<<<gridPC, 256, 0, stream>>>(h, mesh, N, Np, Aw, Bw);
  k2_scan  <<<P,      256, 0, stream>>>(Aw, Bw, Sw, raw_density, N, Np, Dws);
  k3_states<<<gridPC, 256, 0, stream>>>(h, mesh, raw_density, Sw, N, Np, Mpart);
  k4_final <<<(T + 255) / 256, 256, 0, stream>>>(Mpart, h, Dws, raw_offset,
                                                 raw_scale, raw_slope, W, out);
}

// Round 2
// 42.647 us; speedup vs baseline: 1.0986x; 1.0986x over previous
//
#include <hip/hip_runtime.h>
#include <hip/hip_bf16.h>
#include <stdint.h>

#define TSTEPS   4096
#define C_CHUNKS 128
#define L_STEPS  32          // TSTEPS / C_CHUNKS
#define JPAD     128         // padded row width of the g-table (101 used)

__device__ __forceinline__ float fast_exp2(float x){ return __builtin_amdgcn_exp2f(x); }
__device__ __forceinline__ float fast_rcp (float x){ return __builtin_amdgcn_rcpf(x); }
__device__ __forceinline__ float sigmoid_f(float x){
  return fast_rcp(1.0f + fast_exp2(-1.4426950408889634f * x));
}

// K0: build the fused g-table, the up-mask, D = sum(sigmoid(density)), and the
// affine base of the output.
//   tab[t][j] = up_t ?  sigmoid((h_t - j*0.01)/temp)     (alpha table, +g)
//            : -sigmoid((j*0.01 - h_t)/temp)             (beta  table, -g)
// Then a step is s' = (1-|v|)*s + v for v = tab[t][idx], idx = up? ia : ib.
__global__ __launch_bounds__(256) void k0_prep(
    const float* __restrict__ h, const float* __restrict__ raw_density,
    const float* __restrict__ raw_offset, const float* __restrict__ raw_scale,
    const float* __restrict__ raw_slope,
    int N, float* __restrict__ tab, uint32_t* __restrict__ umask,
    float* __restrict__ Dws, float* __restrict__ out)
{
  const int tid = threadIdx.x;
  const int c   = blockIdx.x;           // one block per chunk of 32 t
  const int t0  = c * L_STEPS;
  const float C = 144.26950408889634f;  // (1/temp) * log2(e)

  // up-mask for this chunk (wave 0, lanes 0..31)
  if (tid < 64) {
    const int  l    = tid;
    const int  t    = t0 + l;
    bool bit = false;
    if (l < L_STEPS) {
      const float ht = h[t];
      const float hp = (t > 0) ? h[t - 1] : 0.0f;
      bit = ht > hp;
    }
    const uint64_t m = __ballot(bit);
    if (l == 0) umask[c] = (uint32_t)(m & 0xffffffffull);
  }

  // table rows t0..t0+31 (32 t x 128 j = 4096 items, 16 per thread)
  #pragma unroll
  for (int pass = 0; pass < 16; ++pass) {
    const int item = pass * 256 + tid;
    const int trel = item >> 7;        // /128
    const int j    = item & 127;
    if (j <= 100) {
      const int   t  = t0 + trel;
      const float ht = h[t];
      const float hp = (t > 0) ? h[t - 1] : 0.0f;
      const bool  up = ht > hp;
      const float x  = (float)j * 0.01f;
      const float arg = up ? (x - ht) * C : (ht - x) * C;
      const float g   = fast_rcp(1.0f + fast_exp2(arg));
      tab[(size_t)t * JPAD + j] = up ? g : -g;
    }
  }

  // block 0: density normalizer + output affine base
  if (c == 0) {
    __shared__ float red[256];
    float loc = 0.f;
    for (int j = tid; j < N; j += 256) loc += sigmoid_f(raw_density[j]);
    red[tid] = loc;
    __syncthreads();
    for (int st = 128; st > 0; st >>= 1) {
      if (tid < st) red[tid] += red[tid + st];
      __syncthreads();
    }
    if (tid == 0) Dws[0] = red[0];
    const float offset = -10.0f + 20.0f * sigmoid_f(raw_offset[0]);
    const float slope  = -20.0f + 40.0f * sigmoid_f(raw_slope[0]);
    for (int t = tid; t < TSTEPS; t += 256) out[t] = fmaf(h[t], slope, offset);
  }
}

// K1: per (point, chunk) affine composition over L_STEPS steps via table.
__global__ __launch_bounds__(256) void k1_affine(
    const float* __restrict__ tab, const uint32_t* __restrict__ umask,
    const float* __restrict__ mesh,
    int N, int Np, float* __restrict__ Aw, float* __restrict__ Bw)
{
  const int tid = threadIdx.x;
  const int i   = blockIdx.x * 256 + tid;
  const int c   = blockIdx.y;

  float beta = 0.f, alpha = 0.f;
  if (i < N) { beta = mesh[2*i]; alpha = mesh[2*i+1]; }
  const int ia = (int)(alpha * 100.0f + 0.5f);
  const int ib = (int)(beta  * 100.0f + 0.5f);

  const uint32_t um   = umask[c];
  const float*   tabc = tab + (size_t)c * L_STEPS * JPAD;

  float A = 1.0f, B = 0.0f;
  #pragma unroll
  for (int tl = 0; tl < L_STEPS; ++tl) {
    const int   idx = ((um >> tl) & 1u) ? ia : ib;
    const float v   = tabc[tl * JPAD + idx];
    const float a   = 1.0f - fabsf(v);
    A = A * a;
    B = fmaf(a, B, v);
  }
  Aw[(size_t)c * Np + i] = A;
  Bw[(size_t)c * Np + i] = B;
}

// K2: sequential scan over chunks per point (writes chunk-start states).
__global__ __launch_bounds__(256) void k2_scan(
    const float* __restrict__ Aw, const float* __restrict__ Bw,
    float* __restrict__ Sw, int Np)
{
  const int i = blockIdx.x * 256 + threadIdx.x;
  float s = -1.0f;
  #pragma unroll 8
  for (int c = 0; c < C_CHUNKS; ++c) {
    const size_t off = (size_t)c * Np + i;
    Sw[off] = s;
    s = fmaf(Aw[off], s, Bw[off]);
  }
}

// K3: recompute states per chunk from the chunk-start state, weight by d_i,
// butterfly transpose-reduce over the wave's 64 points, atomicAdd into out.
__global__ __launch_bounds__(256) void k3_states(
    const float* __restrict__ tab, const uint32_t* __restrict__ umask,
    const float* __restrict__ mesh, const float* __restrict__ raw_density,
    const float* __restrict__ Sw, const float* __restrict__ Dws,
    const float* __restrict__ raw_scale,
    int N, int Np, float* __restrict__ out)
{
  const int tid  = threadIdx.x;
  const int i    = blockIdx.x * 256 + tid;
  const int c    = blockIdx.y;
  const int lane = tid & 63;
  const int t0   = c * L_STEPS;

  float beta = 0.f, alpha = 0.f, d = 0.f;
  if (i < N) { beta = mesh[2*i]; alpha = mesh[2*i+1]; d = sigmoid_f(raw_density[i]); }
  const int ia = (int)(alpha * 100.0f + 0.5f);
  const int ib = (int)(beta  * 100.0f + 0.5f);

  const uint32_t um   = umask[c];
  const float*   tabc = tab + (size_t)c * L_STEPS * JPAD;

  float s = Sw[(size_t)c * Np + i];
  float cur[L_STEPS];
  #pragma unroll
  for (int tl = 0; tl < L_STEPS; ++tl) {
    const int   idx = ((um >> tl) & 1u) ? ia : ib;
    const float v   = tabc[tl * JPAD + idx];
    const float a   = 1.0f - fabsf(v);
    s = fmaf(a, s, v);
    cur[tl] = d * s;
  }

  // transpose-reduce: 5 stages over cur[32], then fold the two half-waves.
  // Lane l (l<32) ends holding sum over the wave's 64 points of cur[l].
  #pragma unroll
  for (int k = 0; k < 5; ++k) {
    const bool bb = (lane >> k) & 1;
    #pragma unroll
    for (int j = 0; j < (L_STEPS >> (k + 1)); ++j) {
      const float x = bb ? cur[2*j + 1] : cur[2*j];
      const float y = bb ? cur[2*j]     : cur[2*j + 1];
      cur[j] = x + __shfl_xor(y, 1 << k, 64);
    }
  }
  const float val = cur[0] + __shfl_xor(cur[0], 32, 64);

  const float scale = 20.0f * sigmoid_f(raw_scale[0]);
  const float coef  = scale / Dws[0];
  if (lane < L_STEPS) atomicAdd(&out[t0 + lane], coef * val);
}

extern "C" void kernel_launch(void* const* d_in, const int* in_sizes, int n_in,
                              void* d_out, int out_size, void* d_ws, size_t ws_size,
                              hipStream_t stream)
{
  const float* h           = (const float*)d_in[0];
  const float* mesh        = (const float*)d_in[1];
  const float* raw_density = (const float*)d_in[2];
  const float* raw_offset  = (const float*)d_in[3];
  const float* raw_scale   = (const float*)d_in[4];
  const float* raw_slope   = (const float*)d_in[5];
  float* out = (float*)d_out;

  const int N  = in_sizes[2];          // 5151 mesh points
  const int P  = (N + 255) / 256;      // 21 point-blocks
  const int Np = P * 256;              // 5376 padded points

  float* ws   = (float*)d_ws;
  float* tab  = ws;                                    // TSTEPS*JPAD
  float* Aw   = tab + (size_t)TSTEPS * JPAD;           // C*Np
  float* Bw   = Aw  + (size_t)C_CHUNKS * Np;           // C*Np
  float* Sw   = Bw  + (size_t)C_CHUNKS * Np;           // C*Np
  float* Dws  = Sw  + (size_t)C_CHUNKS * Np;           // 1
  uint32_t* umask = (uint32_t*)(Dws + 1);              // C_CHUNKS

  dim3 gridPC(P, C_CHUNKS);
  k0_prep  <<<C_CHUNKS, 256, 0, stream>>>(h, raw_density, raw_offset, raw_scale,
                                          raw_slope, N, tab, umask, Dws, out);
  k1_affine<<<gridPC,  256, 0, stream>>>(tab, umask, mesh, N, Np, Aw, Bw);
  k2_scan  <<<P,       256, 0, stream>>>(Aw, Bw, Sw, Np);
  k3_states<<<gridPC,  256, 0, stream>>>(tab, umask, mesh, raw_density, Sw, Dws,
                                         raw_scale, N, Np, out);
}